// Round 5
// baseline (103.678 us; speedup 1.0000x reference)
//
#include <hip/hip_runtime.h>
#include <hip/hip_bf16.h>

// GAT, 2 layers, N=8192 nodes, sparse adjacency (~270K edges incl. self-loops).
// Masked softmax with -1e9 fill == sparse neighbor softmax (exp underflows to 0).
// All fp32. Round 4: replace hipMemsetAsync (rocclr fill ran at 190 GB/s = 44us)
// with a grid-stride uint4 zero kernel (~2us).
// Workspace layout (~24.8 MB):
//   [0,8MB)    h1[8192][256]
//   [8,16MB)   out1[8192][256]  (post-ELU layer-1 output)
//   [16,24MB)  bitmap[8192][256] uint32  -> reused as nbr ushort[8192][512]
//   [24MB..)   f1s[8192], f1d[8192], h2[8192][16], f2s[8192], f2d[8192], deg[8192]

#define NN 8192
#define MAXD 128  // slots handled in weight phase; P(in-degree>128) ~ 1e-18

// ---------- fast zero of the 8MB bitmap ----------
__global__ __launch_bounds__(256) void zero_bitmap_kernel(uint4* __restrict__ p) {
  p[blockIdx.x * 256 + threadIdx.x] = uint4{0u, 0u, 0u, 0u};
}

// ---------- GEMM1: h1 = x(8192x512) @ W1(512x256), fp32 ----------
__global__ __launch_bounds__(256) void gemm1_kernel(const float* __restrict__ A,
                                                    const float* __restrict__ B,
                                                    float* __restrict__ C) {
  constexpr int K = 512, N = 256;
  __shared__ float As[16][68];
  __shared__ float Bs[16][68];
  const int tid = threadIdx.x;
  const int bm = blockIdx.x * 64;
  const int bn = blockIdx.y * 64;
  const int tx = tid & 15, ty = tid >> 4;
  const int arow = tid >> 2, acol = (tid & 3) << 2;
  const int brow = tid >> 4, bcol = (tid & 15) << 2;
  float acc[4][4] = {};
  for (int k0 = 0; k0 < K; k0 += 16) {
    const float4 av = *(const float4*)(A + (size_t)(bm + arow) * K + (k0 + acol));
    const float4 bv = *(const float4*)(B + (size_t)(k0 + brow) * N + (bn + bcol));
    __syncthreads();
    As[acol + 0][arow] = av.x;
    As[acol + 1][arow] = av.y;
    As[acol + 2][arow] = av.z;
    As[acol + 3][arow] = av.w;
    *(float4*)&Bs[brow][bcol] = bv;
    __syncthreads();
#pragma unroll
    for (int kk = 0; kk < 16; ++kk) {
      const float4 a4 = *(const float4*)&As[kk][ty << 2];
      const float4 b4 = *(const float4*)&Bs[kk][tx << 2];
      const float ar[4] = {a4.x, a4.y, a4.z, a4.w};
      const float br[4] = {b4.x, b4.y, b4.z, b4.w};
#pragma unroll
      for (int i = 0; i < 4; ++i)
#pragma unroll
        for (int j = 0; j < 4; ++j) acc[i][j] = fmaf(ar[i], br[j], acc[i][j]);
    }
  }
#pragma unroll
  for (int i = 0; i < 4; ++i) {
    float4 v = {acc[i][0], acc[i][1], acc[i][2], acc[i][3]};
    *(float4*)(C + (size_t)(bm + (ty << 2) + i) * N + bn + (tx << 2)) = v;
  }
}

// ---------- f1: per-row dots of h1 with a1_src / a1_dst ----------
__global__ __launch_bounds__(256) void f1_kernel(const float* __restrict__ h1,
                                                 const float* __restrict__ a_src,
                                                 const float* __restrict__ a_dst,
                                                 float* __restrict__ fs,
                                                 float* __restrict__ fd) {
  const int lane = threadIdx.x & 63;
  const int row = blockIdx.x * 4 + (threadIdx.x >> 6);
  const float4 hv = *(const float4*)(h1 + (size_t)row * 256 + lane * 4);
  const float4 as = *(const float4*)(a_src + lane * 4);
  const float4 ad = *(const float4*)(a_dst + lane * 4);
  float ss = hv.x * as.x + hv.y * as.y + hv.z * as.z + hv.w * as.w;
  float dd = hv.x * ad.x + hv.y * ad.y + hv.z * ad.z + hv.w * ad.w;
#pragma unroll
  for (int off = 32; off; off >>= 1) {
    ss += __shfl_xor(ss, off);
    dd += __shfl_xor(dd, off);
  }
  if (lane == 0) {
    fs[row] = ss;
    fd[row] = dd;
  }
}

// ---------- scatter edges into bitmap (dedup via OR) ----------
__global__ void scatter_kernel(const int* __restrict__ ei, int E,
                               unsigned* __restrict__ bitmap) {
  const int t = blockIdx.x * 256 + threadIdx.x;
  if (t >= E) return;
  const int s = ei[t];
  const int d = ei[E + t];
  atomicOr(bitmap + (size_t)s * 256 + (d >> 5), 1u << (d & 31));
}

// ---------- build CSR in place over the bitmap ----------
// One wave per row. Each lane loads 4 consecutive words (uint4, one vector
// load instruction -> all reads complete before any store issues), popcount +
// shuffle prefix-scan gives each lane its write offset, then ushort neighbor
// indices are written into the row's own 1KB (dead bitmap storage).
__global__ __launch_bounds__(256) void build_csr_kernel(unsigned* __restrict__ bitmap,
                                                        int* __restrict__ deg) {
  const int lane = threadIdx.x & 63;
  const int row = blockIdx.x * 4 + (threadIdx.x >> 6);
  unsigned* brow = bitmap + (size_t)row * 256;
  const uint4 wv = *(const uint4*)(brow + lane * 4);
  const int cnt = __popc(wv.x) + __popc(wv.y) + __popc(wv.z) + __popc(wv.w);
  int inc = cnt;
#pragma unroll
  for (int d = 1; d < 64; d <<= 1) {
    const int t = __shfl_up(inc, d);
    if (lane >= d) inc += t;
  }
  int off = inc - cnt;  // exclusive prefix
  const int total = __shfl(inc, 63);
  unsigned short* nb = (unsigned short*)brow;
  const unsigned words[4] = {wv.x, wv.y, wv.z, wv.w};
  const int base_j = lane * 128;
#pragma unroll
  for (int q = 0; q < 4; ++q) {
    unsigned word = words[q];
    while (word) {
      const int b = __ffs(word) - 1;
      word &= word - 1;
      nb[off++] = (unsigned short)(base_j + q * 32 + b);
    }
  }
  if (lane == 0) deg[row] = total;
}

__device__ __forceinline__ float lrelu02(float e) { return e > 0.f ? e : 0.2f * e; }

// ---------- layer-1 attention: parallel weights + x4-unrolled gather ----------
__global__ __launch_bounds__(256) void attn1_kernel(const unsigned* __restrict__ bitmap,
                                                    const int* __restrict__ degarr,
                                                    const float* __restrict__ h1,
                                                    const float* __restrict__ fs,
                                                    const float* __restrict__ fd,
                                                    float* __restrict__ out1) {
  __shared__ float wsh[4][MAXD];
  __shared__ int jsh[4][MAXD];
  const int lane = threadIdx.x & 63;
  const int wv = threadIdx.x >> 6;
  const int row = blockIdx.x * 4 + wv;
  const unsigned short* nb = (const unsigned short*)(bitmap + (size_t)row * 256);
  const int deg = degarr[row];
  const float fsr = fs[row];
  // ---- weight phase: lane k handles neighbors k and k+64 in parallel ----
  const int j0 = (lane < deg) ? (int)nb[lane] : 0;
  const int j1 = (lane + 64 < deg) ? (int)nb[lane + 64] : 0;
  const float e0 = (lane < deg) ? lrelu02(fsr + fd[j0]) : -1e30f;
  const float e1 = (lane + 64 < deg) ? lrelu02(fsr + fd[j1]) : -1e30f;
  float m = fmaxf(e0, e1);
#pragma unroll
  for (int off = 32; off; off >>= 1) m = fmaxf(m, __shfl_xor(m, off));
  const float w0 = (lane < deg) ? expf(e0 - m) : 0.f;
  const float w1 = (lane + 64 < deg) ? expf(e1 - m) : 0.f;
  float s = w0 + w1;
#pragma unroll
  for (int off = 32; off; off >>= 1) s += __shfl_xor(s, off);
  wsh[wv][lane] = w0;
  jsh[wv][lane] = j0;
  wsh[wv][lane + 64] = w1;
  jsh[wv][lane + 64] = j1;
  // same-wave LDS produce->consume; compiler inserts lgkmcnt, no barrier needed
  // ---- gather phase: 4 independent loads in flight ----
  float4 acc = {0.f, 0.f, 0.f, 0.f};
  int t = 0;
  for (; t + 4 <= deg; t += 4) {
    const float W0 = wsh[wv][t], W1 = wsh[wv][t + 1], W2 = wsh[wv][t + 2], W3 = wsh[wv][t + 3];
    const int J0 = jsh[wv][t], J1 = jsh[wv][t + 1], J2 = jsh[wv][t + 2], J3 = jsh[wv][t + 3];
    const float4 v0 = *(const float4*)(h1 + (size_t)J0 * 256 + lane * 4);
    const float4 v1 = *(const float4*)(h1 + (size_t)J1 * 256 + lane * 4);
    const float4 v2 = *(const float4*)(h1 + (size_t)J2 * 256 + lane * 4);
    const float4 v3 = *(const float4*)(h1 + (size_t)J3 * 256 + lane * 4);
    acc.x = fmaf(W0, v0.x, fmaf(W1, v1.x, fmaf(W2, v2.x, fmaf(W3, v3.x, acc.x))));
    acc.y = fmaf(W0, v0.y, fmaf(W1, v1.y, fmaf(W2, v2.y, fmaf(W3, v3.y, acc.y))));
    acc.z = fmaf(W0, v0.z, fmaf(W1, v1.z, fmaf(W2, v2.z, fmaf(W3, v3.z, acc.z))));
    acc.w = fmaf(W0, v0.w, fmaf(W1, v1.w, fmaf(W2, v2.w, fmaf(W3, v3.w, acc.w))));
  }
  for (; t < deg; ++t) {
    const float W0 = wsh[wv][t];
    const int J0 = jsh[wv][t];
    const float4 v0 = *(const float4*)(h1 + (size_t)J0 * 256 + lane * 4);
    acc.x = fmaf(W0, v0.x, acc.x);
    acc.y = fmaf(W0, v0.y, acc.y);
    acc.z = fmaf(W0, v0.z, acc.z);
    acc.w = fmaf(W0, v0.w, acc.w);
  }
  const float inv = 1.f / s;
  float4 v = {acc.x * inv, acc.y * inv, acc.z * inv, acc.w * inv};
  v.x = v.x > 0.f ? v.x : expf(v.x) - 1.f;  // elu
  v.y = v.y > 0.f ? v.y : expf(v.y) - 1.f;
  v.z = v.z > 0.f ? v.z : expf(v.z) - 1.f;
  v.w = v.w > 0.f ? v.w : expf(v.w) - 1.f;
  *(float4*)(out1 + (size_t)row * 256 + lane * 4) = v;
}

// ---------- GEMM2: h2 = out1(8192x256) @ W2(256x16) ----------
__global__ __launch_bounds__(256) void gemm2_kernel(const float* __restrict__ out1,
                                                    const float* __restrict__ W2,
                                                    float* __restrict__ h2) {
  __shared__ float Ws[256 * 16];
  for (int i = threadIdx.x; i < 256 * 16; i += 256) Ws[i] = W2[i];
  __syncthreads();
  const int r = threadIdx.x >> 4, c = threadIdx.x & 15;
  const int row = blockIdx.x * 16 + r;
  const float* arow = out1 + (size_t)row * 256;
  float acc = 0.f;
#pragma unroll 8
  for (int k = 0; k < 256; ++k) acc = fmaf(arow[k], Ws[k * 16 + c], acc);
  h2[(size_t)row * 16 + c] = acc;
}

// ---------- f2: per-row dots of h2 with a2_src / a2_dst ----------
__global__ void f2_kernel(const float* __restrict__ h2, const float* __restrict__ a_src,
                          const float* __restrict__ a_dst, float* __restrict__ fs,
                          float* __restrict__ fd) {
  const int row = blockIdx.x * blockDim.x + threadIdx.x;
  if (row >= NN) return;
  float s = 0.f, d = 0.f;
#pragma unroll
  for (int k = 0; k < 16; ++k) {
    const float h = h2[(size_t)row * 16 + k];
    s = fmaf(h, a_src[k], s);
    d = fmaf(h, a_dst[k], d);
  }
  fs[row] = s;
  fd[row] = d;
}

// ---------- layer-2 attention + final log_softmax over 16 classes ----------
__global__ __launch_bounds__(256) void attn2_kernel(const unsigned* __restrict__ bitmap,
                                                    const int* __restrict__ degarr,
                                                    const float* __restrict__ h2,
                                                    const float* __restrict__ fs,
                                                    const float* __restrict__ fd,
                                                    float* __restrict__ out) {
  __shared__ float wsh[4][MAXD];
  __shared__ int jsh[4][MAXD];
  const int lane = threadIdx.x & 63;
  const int wv = threadIdx.x >> 6;
  const int row = blockIdx.x * 4 + wv;
  const unsigned short* nb = (const unsigned short*)(bitmap + (size_t)row * 256);
  const int deg = degarr[row];
  const float fsr = fs[row];
  // ---- weight phase (same as attn1) ----
  const int j0 = (lane < deg) ? (int)nb[lane] : 0;
  const int j1 = (lane + 64 < deg) ? (int)nb[lane + 64] : 0;
  const float e0 = (lane < deg) ? lrelu02(fsr + fd[j0]) : -1e30f;
  const float e1 = (lane + 64 < deg) ? lrelu02(fsr + fd[j1]) : -1e30f;
  float m = fmaxf(e0, e1);
#pragma unroll
  for (int off = 32; off; off >>= 1) m = fmaxf(m, __shfl_xor(m, off));
  const float w0 = (lane < deg) ? expf(e0 - m) : 0.f;
  const float w1 = (lane + 64 < deg) ? expf(e1 - m) : 0.f;
  float s = w0 + w1;
#pragma unroll
  for (int off = 32; off; off >>= 1) s += __shfl_xor(s, off);
  wsh[wv][lane] = w0;
  jsh[wv][lane] = j0;
  wsh[wv][lane + 64] = w1;
  jsh[wv][lane + 64] = j1;
  // ---- gather: 4 neighbors at a time (lane = group*16 + class), unroll x2 ----
  const int c = lane & 15, g = lane >> 4;
  float acc = 0.f;
  int t = g;
  for (; t + 4 < deg; t += 8) {
    const float W0 = wsh[wv][t], W1 = wsh[wv][t + 4];
    const float v0 = h2[(size_t)jsh[wv][t] * 16 + c];
    const float v1 = h2[(size_t)jsh[wv][t + 4] * 16 + c];
    acc = fmaf(W0, v0, fmaf(W1, v1, acc));
  }
  if (t < deg) acc = fmaf(wsh[wv][t], h2[(size_t)jsh[wv][t] * 16 + c], acc);
  acc += __shfl_xor(acc, 16);
  acc += __shfl_xor(acc, 32);
  const float v = acc / s;  // logits (all lanes hold their class-c value)
  // log_softmax across the 16 classes
  float mx = v;
#pragma unroll
  for (int off = 8; off; off >>= 1) mx = fmaxf(mx, __shfl_xor(mx, off, 16));
  float se = expf(v - mx);
#pragma unroll
  for (int off = 8; off; off >>= 1) se += __shfl_xor(se, off, 16);
  if (lane < 16) out[(size_t)row * 16 + lane] = v - mx - logf(se);
}

extern "C" void kernel_launch(void* const* d_in, const int* in_sizes, int n_in,
                              void* d_out, int out_size, void* d_ws, size_t ws_size,
                              hipStream_t stream) {
  const float* x = (const float*)d_in[0];
  const int* ei = (const int*)d_in[1];
  const float* W1 = (const float*)d_in[2];
  const float* a1s = (const float*)d_in[3];
  const float* a1d = (const float*)d_in[4];
  const float* W2 = (const float*)d_in[5];
  const float* a2s = (const float*)d_in[6];
  const float* a2d = (const float*)d_in[7];
  float* out = (float*)d_out;
  const int E = in_sizes[1] / 2;

  char* ws = (char*)d_ws;
  float* h1 = (float*)ws;                              // 8 MB
  float* out1 = (float*)(ws + (8u << 20));             // 8 MB
  unsigned* bitmap = (unsigned*)(ws + (16u << 20));    // 8 MB, reused as CSR
  float* f1s = (float*)(ws + (24u << 20));
  float* f1d = f1s + NN;
  float* h2 = f1d + NN;                                // 512 KB
  float* f2s = h2 + (size_t)NN * 16;
  float* f2d = f2s + NN;
  int* deg = (int*)(f2d + NN);

  // zero the 8MB bitmap: 2048 blocks x 256 threads x 16B = 8MB exactly
  zero_bitmap_kernel<<<2048, 256, 0, stream>>>((uint4*)bitmap);
  scatter_kernel<<<(E + 255) / 256, 256, 0, stream>>>(ei, E, bitmap);
  build_csr_kernel<<<NN / 4, 256, 0, stream>>>(bitmap, deg);
  gemm1_kernel<<<dim3(NN / 64, 256 / 64), 256, 0, stream>>>(x, W1, h1);
  f1_kernel<<<NN / 4, 256, 0, stream>>>(h1, a1s, a1d, f1s, f1d);
  attn1_kernel<<<NN / 4, 256, 0, stream>>>(bitmap, deg, h1, f1s, f1d, out1);
  gemm2_kernel<<<NN / 16, 256, 0, stream>>>(out1, W2, h2);
  f2_kernel<<<NN / 256, 256, 0, stream>>>(h2, a2s, a2d, f2s, f2d);
  attn2_kernel<<<NN / 4, 256, 0, stream>>>(bitmap, deg, h2, f2s, f2d, out);
}

// Round 6
// 87.235 us; speedup vs baseline: 1.1885x; 1.1885x over previous
//
#include <hip/hip_runtime.h>
#include <hip/hip_bf16.h>

// GAT, 2 layers, N=8192 nodes, sparse adjacency (~270K edges incl. self-loops).
// Masked softmax with -1e9 fill == sparse neighbor softmax (exp underflows to 0).
// Round 6: gemm1 -> bf16 MFMA (fp32 accum); h1 kept as bf16 (halves attn1
// gather traffic). Rest fp32. Harness's 256MB ws-poison fill (~42us) is not
// ours to remove.
// Workspace layout (~26 MB):
//   [0,4MB)    h1b[8192][256] bf16
//   [8,16MB)   out1[8192][256] f32 (post-ELU layer-1 output)
//   [16,24MB)  bitmap[8192][256] u32 -> reused as nbr ushort[8192][512]
//   [24MB..)   f1s, f1d, h2[8192][16], f2s, f2d, deg, w1t[256][512] bf16

#define NN 8192
#define MAXD 128  // weight-phase slots; P(in-degree>128) ~ 1e-18 (Poisson 32)

typedef __bf16 bf16x8 __attribute__((ext_vector_type(8)));
typedef float f32x4 __attribute__((ext_vector_type(4)));
typedef unsigned short u16x8 __attribute__((ext_vector_type(8)));

__device__ __forceinline__ unsigned short f2bf(float f) {
  unsigned u = __float_as_uint(f);
  unsigned r = (u + 0x7fffu + ((u >> 16) & 1u)) >> 16;  // round-nearest-even
  return (unsigned short)r;
}
__device__ __forceinline__ float bf2f(unsigned short u) {
  return __uint_as_float(((unsigned)u) << 16);
}
__device__ __forceinline__ float lrelu02(float e) { return e > 0.f ? e : 0.2f * e; }

// ---------- fast zero of the 8MB bitmap ----------
__global__ __launch_bounds__(256) void zero_bitmap_kernel(uint4* __restrict__ p) {
  p[blockIdx.x * 256 + threadIdx.x] = uint4{0u, 0u, 0u, 0u};
}

// ---------- W1 [512][256] f32 -> W1t [256][512] bf16 (n-major, k-contiguous) ----------
__global__ __launch_bounds__(256) void w1t_kernel(const float* __restrict__ W1,
                                                  unsigned short* __restrict__ W1t) {
  const int gid = blockIdx.x * 256 + threadIdx.x;  // 131072 total
  const int n = gid >> 9, k = gid & 511;
  W1t[gid] = f2bf(W1[(size_t)k * 256 + n]);
}

// ---------- GEMM1 (MFMA): h1b = bf16( x(8192x512) @ W1(512x256) ) ----------
// Block: 256 thr (4 waves), tile BM=128 x BN=64, BK=64, fp32 accum.
// LDS unit map (16B units of 8 bf16): for a 16-row block rb, k-step ks, lane l
// reads unit rb*128 + ks*64 + l  (lane-sequential -> conflict-free b128 reads).
// Staging writes unit u(row,c) = (row>>4)*128 + (c>>2)*64 + (c&3)*16 + (row&15),
// c = 16B k-chunk index (0..7). A and B tiles share the map (B from W1t rows).
__global__ __launch_bounds__(256) void gemm1_mfma_kernel(
    const float* __restrict__ X, const unsigned short* __restrict__ W1t,
    unsigned short* __restrict__ h1b) {
  constexpr int K = 512;
  __shared__ __align__(16) unsigned short lds[(128 * 64) + (64 * 64)];  // 24 KB
  const int t = threadIdx.x;
  const int w = t >> 6, l = t & 63;
  const int bm = blockIdx.x * 128, bn = blockIdx.y * 64;
  const int r8 = t >> 3, c8 = t & 7;  // staging coords

  f32x4 acc[2][4];
  const f32x4 fz = {0.f, 0.f, 0.f, 0.f};
#pragma unroll
  for (int i = 0; i < 2; ++i)
#pragma unroll
    for (int j = 0; j < 4; ++j) acc[i][j] = fz;

  for (int k0 = 0; k0 < K; k0 += 64) {
    // ---- issue global loads before the barrier (overlap prev compute) ----
    float4 xa[4][2];
#pragma unroll
    for (int p = 0; p < 4; ++p) {
      const float* s = X + (size_t)(bm + r8 + p * 32) * K + k0 + c8 * 8;
      xa[p][0] = *(const float4*)s;
      xa[p][1] = *(const float4*)(s + 4);
    }
    uint4 wb[2];
#pragma unroll
    for (int p = 0; p < 2; ++p)
      wb[p] = *(const uint4*)(W1t + (size_t)(bn + r8 + p * 32) * K + k0 + c8 * 8);
    __syncthreads();  // prev tile's LDS reads done
    // ---- convert + write to LDS ----
#pragma unroll
    for (int p = 0; p < 4; ++p) {
      const int row = r8 + p * 32;
      const int u = ((row >> 4) << 7) + ((c8 >> 2) << 6) + ((c8 & 3) << 4) + (row & 15);
      u16x8 v;
      v[0] = f2bf(xa[p][0].x); v[1] = f2bf(xa[p][0].y);
      v[2] = f2bf(xa[p][0].z); v[3] = f2bf(xa[p][0].w);
      v[4] = f2bf(xa[p][1].x); v[5] = f2bf(xa[p][1].y);
      v[6] = f2bf(xa[p][1].z); v[7] = f2bf(xa[p][1].w);
      *(u16x8*)(lds + u * 8) = v;
    }
#pragma unroll
    for (int p = 0; p < 2; ++p) {
      const int col = r8 + p * 32;
      const int u = 1024 + ((col >> 4) << 7) + ((c8 >> 2) << 6) + ((c8 & 3) << 4) + (col & 15);
      *(uint4*)(lds + u * 8) = wb[p];
    }
    __syncthreads();
    // ---- MFMA: wave w owns rows [32w,32w+32) x cols [0,64) ----
#pragma unroll
    for (int ks = 0; ks < 2; ++ks) {
      const bf16x8 a0 = *(const bf16x8*)(lds + ((w * 2 + 0) * 128 + ks * 64 + l) * 8);
      const bf16x8 a1 = *(const bf16x8*)(lds + ((w * 2 + 1) * 128 + ks * 64 + l) * 8);
      const bf16x8 b0 = *(const bf16x8*)(lds + (1024 + 0 * 128 + ks * 64 + l) * 8);
      const bf16x8 b1 = *(const bf16x8*)(lds + (1024 + 1 * 128 + ks * 64 + l) * 8);
      const bf16x8 b2 = *(const bf16x8*)(lds + (1024 + 2 * 128 + ks * 64 + l) * 8);
      const bf16x8 b3 = *(const bf16x8*)(lds + (1024 + 3 * 128 + ks * 64 + l) * 8);
      acc[0][0] = __builtin_amdgcn_mfma_f32_16x16x32_bf16(a0, b0, acc[0][0], 0, 0, 0);
      acc[0][1] = __builtin_amdgcn_mfma_f32_16x16x32_bf16(a0, b1, acc[0][1], 0, 0, 0);
      acc[0][2] = __builtin_amdgcn_mfma_f32_16x16x32_bf16(a0, b2, acc[0][2], 0, 0, 0);
      acc[0][3] = __builtin_amdgcn_mfma_f32_16x16x32_bf16(a0, b3, acc[0][3], 0, 0, 0);
      acc[1][0] = __builtin_amdgcn_mfma_f32_16x16x32_bf16(a1, b0, acc[1][0], 0, 0, 0);
      acc[1][1] = __builtin_amdgcn_mfma_f32_16x16x32_bf16(a1, b1, acc[1][1], 0, 0, 0);
      acc[1][2] = __builtin_amdgcn_mfma_f32_16x16x32_bf16(a1, b2, acc[1][2], 0, 0, 0);
      acc[1][3] = __builtin_amdgcn_mfma_f32_16x16x32_bf16(a1, b3, acc[1][3], 0, 0, 0);
    }
  }
  // ---- epilogue: C/D layout row=(l>>4)*4+q, col=l&15 (m89-verified) ----
#pragma unroll
  for (int i = 0; i < 2; ++i)
#pragma unroll
    for (int j = 0; j < 4; ++j)
#pragma unroll
      for (int q = 0; q < 4; ++q) {
        const int row = bm + w * 32 + i * 16 + (l >> 4) * 4 + q;
        const int col = bn + j * 16 + (l & 15);
        h1b[(size_t)row * 256 + col] = f2bf(acc[i][j][q]);
      }
}

// ---------- f1: per-row dots of h1b with a1_src / a1_dst ----------
__global__ __launch_bounds__(256) void f1_kernel(const unsigned short* __restrict__ h1b,
                                                 const float* __restrict__ a_src,
                                                 const float* __restrict__ a_dst,
                                                 float* __restrict__ fs,
                                                 float* __restrict__ fd) {
  const int lane = threadIdx.x & 63;
  const int row = blockIdx.x * 4 + (threadIdx.x >> 6);
  const ushort4 hv = *(const ushort4*)(h1b + (size_t)row * 256 + lane * 4);
  const float h0 = bf2f(hv.x), h1 = bf2f(hv.y), h2 = bf2f(hv.z), h3 = bf2f(hv.w);
  const float4 as = *(const float4*)(a_src + lane * 4);
  const float4 ad = *(const float4*)(a_dst + lane * 4);
  float ss = h0 * as.x + h1 * as.y + h2 * as.z + h3 * as.w;
  float dd = h0 * ad.x + h1 * ad.y + h2 * ad.z + h3 * ad.w;
#pragma unroll
  for (int off = 32; off; off >>= 1) {
    ss += __shfl_xor(ss, off);
    dd += __shfl_xor(dd, off);
  }
  if (lane == 0) {
    fs[row] = ss;
    fd[row] = dd;
  }
}

// ---------- scatter edges into bitmap (dedup via OR) ----------
__global__ void scatter_kernel(const int* __restrict__ ei, int E,
                               unsigned* __restrict__ bitmap) {
  const int t = blockIdx.x * 256 + threadIdx.x;
  if (t >= E) return;
  const int s = ei[t];
  const int d = ei[E + t];
  atomicOr(bitmap + (size_t)s * 256 + (d >> 5), 1u << (d & 31));
}

// ---------- build CSR in place over the bitmap ----------
__global__ __launch_bounds__(256) void build_csr_kernel(unsigned* __restrict__ bitmap,
                                                        int* __restrict__ deg) {
  const int lane = threadIdx.x & 63;
  const int row = blockIdx.x * 4 + (threadIdx.x >> 6);
  unsigned* brow = bitmap + (size_t)row * 256;
  const uint4 wv = *(const uint4*)(brow + lane * 4);
  const int cnt = __popc(wv.x) + __popc(wv.y) + __popc(wv.z) + __popc(wv.w);
  int inc = cnt;
#pragma unroll
  for (int d = 1; d < 64; d <<= 1) {
    const int t = __shfl_up(inc, d);
    if (lane >= d) inc += t;
  }
  int off = inc - cnt;  // exclusive prefix
  const int total = __shfl(inc, 63);
  unsigned short* nb = (unsigned short*)brow;
  const unsigned words[4] = {wv.x, wv.y, wv.z, wv.w};
  const int base_j = lane * 128;
#pragma unroll
  for (int q = 0; q < 4; ++q) {
    unsigned word = words[q];
    while (word) {
      const int b = __ffs(word) - 1;
      word &= word - 1;
      nb[off++] = (unsigned short)(base_j + q * 32 + b);
    }
  }
  if (lane == 0) deg[row] = total;
}

// ---------- layer-1 attention: parallel weights + x4-unrolled bf16 gather ----------
__global__ __launch_bounds__(256) void attn1_kernel(const unsigned* __restrict__ bitmap,
                                                    const int* __restrict__ degarr,
                                                    const unsigned short* __restrict__ h1b,
                                                    const float* __restrict__ fs,
                                                    const float* __restrict__ fd,
                                                    float* __restrict__ out1) {
  __shared__ float wsh[4][MAXD];
  __shared__ int jsh[4][MAXD];
  const int lane = threadIdx.x & 63;
  const int wv = threadIdx.x >> 6;
  const int row = blockIdx.x * 4 + wv;
  const unsigned short* nb = (const unsigned short*)(bitmap + (size_t)row * 256);
  const int deg = degarr[row];
  const float fsr = fs[row];
  // ---- weight phase: lane k handles neighbors k and k+64 ----
  const int j0 = (lane < deg) ? (int)nb[lane] : 0;
  const int j1 = (lane + 64 < deg) ? (int)nb[lane + 64] : 0;
  const float e0 = (lane < deg) ? lrelu02(fsr + fd[j0]) : -1e30f;
  const float e1 = (lane + 64 < deg) ? lrelu02(fsr + fd[j1]) : -1e30f;
  float m = fmaxf(e0, e1);
#pragma unroll
  for (int off = 32; off; off >>= 1) m = fmaxf(m, __shfl_xor(m, off));
  const float w0 = (lane < deg) ? expf(e0 - m) : 0.f;
  const float w1 = (lane + 64 < deg) ? expf(e1 - m) : 0.f;
  float s = w0 + w1;
#pragma unroll
  for (int off = 32; off; off >>= 1) s += __shfl_xor(s, off);
  wsh[wv][lane] = w0;
  jsh[wv][lane] = j0;
  wsh[wv][lane + 64] = w1;
  jsh[wv][lane + 64] = j1;
  // same-wave LDS produce->consume; compiler inserts lgkmcnt
  // ---- gather phase: 4 independent 8B loads in flight ----
  float4 acc = {0.f, 0.f, 0.f, 0.f};
  int t = 0;
  for (; t + 4 <= deg; t += 4) {
    const float W0 = wsh[wv][t], W1 = wsh[wv][t + 1], W2 = wsh[wv][t + 2], W3 = wsh[wv][t + 3];
    const int J0 = jsh[wv][t], J1 = jsh[wv][t + 1], J2 = jsh[wv][t + 2], J3 = jsh[wv][t + 3];
    const ushort4 v0 = *(const ushort4*)(h1b + (size_t)J0 * 256 + lane * 4);
    const ushort4 v1 = *(const ushort4*)(h1b + (size_t)J1 * 256 + lane * 4);
    const ushort4 v2 = *(const ushort4*)(h1b + (size_t)J2 * 256 + lane * 4);
    const ushort4 v3 = *(const ushort4*)(h1b + (size_t)J3 * 256 + lane * 4);
    acc.x = fmaf(W0, bf2f(v0.x), fmaf(W1, bf2f(v1.x), fmaf(W2, bf2f(v2.x), fmaf(W3, bf2f(v3.x), acc.x))));
    acc.y = fmaf(W0, bf2f(v0.y), fmaf(W1, bf2f(v1.y), fmaf(W2, bf2f(v2.y), fmaf(W3, bf2f(v3.y), acc.y))));
    acc.z = fmaf(W0, bf2f(v0.z), fmaf(W1, bf2f(v1.z), fmaf(W2, bf2f(v2.z), fmaf(W3, bf2f(v3.z), acc.z))));
    acc.w = fmaf(W0, bf2f(v0.w), fmaf(W1, bf2f(v1.w), fmaf(W2, bf2f(v2.w), fmaf(W3, bf2f(v3.w), acc.w))));
  }
  for (; t < deg; ++t) {
    const float W0 = wsh[wv][t];
    const int J0 = jsh[wv][t];
    const ushort4 v0 = *(const ushort4*)(h1b + (size_t)J0 * 256 + lane * 4);
    acc.x = fmaf(W0, bf2f(v0.x), acc.x);
    acc.y = fmaf(W0, bf2f(v0.y), acc.y);
    acc.z = fmaf(W0, bf2f(v0.z), acc.z);
    acc.w = fmaf(W0, bf2f(v0.w), acc.w);
  }
  const float inv = 1.f / s;
  float4 v = {acc.x * inv, acc.y * inv, acc.z * inv, acc.w * inv};
  v.x = v.x > 0.f ? v.x : expf(v.x) - 1.f;  // elu
  v.y = v.y > 0.f ? v.y : expf(v.y) - 1.f;
  v.z = v.z > 0.f ? v.z : expf(v.z) - 1.f;
  v.w = v.w > 0.f ? v.w : expf(v.w) - 1.f;
  *(float4*)(out1 + (size_t)row * 256 + lane * 4) = v;
}

// ---------- GEMM2: h2 = out1(8192x256) @ W2(256x16), fp32 ----------
__global__ __launch_bounds__(256) void gemm2_kernel(const float* __restrict__ out1,
                                                    const float* __restrict__ W2,
                                                    float* __restrict__ h2) {
  __shared__ float Ws[256 * 16];
  for (int i = threadIdx.x; i < 256 * 16; i += 256) Ws[i] = W2[i];
  __syncthreads();
  const int r = threadIdx.x >> 4, c = threadIdx.x & 15;
  const int row = blockIdx.x * 16 + r;
  const float* arow = out1 + (size_t)row * 256;
  float acc = 0.f;
#pragma unroll 8
  for (int k = 0; k < 256; ++k) acc = fmaf(arow[k], Ws[k * 16 + c], acc);
  h2[(size_t)row * 16 + c] = acc;
}

// ---------- f2: per-row dots of h2 with a2_src / a2_dst ----------
__global__ void f2_kernel(const float* __restrict__ h2, const float* __restrict__ a_src,
                          const float* __restrict__ a_dst, float* __restrict__ fs,
                          float* __restrict__ fd) {
  const int row = blockIdx.x * blockDim.x + threadIdx.x;
  if (row >= NN) return;
  float s = 0.f, d = 0.f;
#pragma unroll
  for (int k = 0; k < 16; ++k) {
    const float h = h2[(size_t)row * 16 + k];
    s = fmaf(h, a_src[k], s);
    d = fmaf(h, a_dst[k], d);
  }
  fs[row] = s;
  fd[row] = d;
}

// ---------- layer-2 attention + final log_softmax over 16 classes ----------
__global__ __launch_bounds__(256) void attn2_kernel(const unsigned* __restrict__ bitmap,
                                                    const int* __restrict__ degarr,
                                                    const float* __restrict__ h2,
                                                    const float* __restrict__ fs,
                                                    const float* __restrict__ fd,
                                                    float* __restrict__ out) {
  __shared__ float wsh[4][MAXD];
  __shared__ int jsh[4][MAXD];
  const int lane = threadIdx.x & 63;
  const int wv = threadIdx.x >> 6;
  const int row = blockIdx.x * 4 + wv;
  const unsigned short* nb = (const unsigned short*)(bitmap + (size_t)row * 256);
  const int deg = degarr[row];
  const float fsr = fs[row];
  const int j0 = (lane < deg) ? (int)nb[lane] : 0;
  const int j1 = (lane + 64 < deg) ? (int)nb[lane + 64] : 0;
  const float e0 = (lane < deg) ? lrelu02(fsr + fd[j0]) : -1e30f;
  const float e1 = (lane + 64 < deg) ? lrelu02(fsr + fd[j1]) : -1e30f;
  float m = fmaxf(e0, e1);
#pragma unroll
  for (int off = 32; off; off >>= 1) m = fmaxf(m, __shfl_xor(m, off));
  const float w0 = (lane < deg) ? expf(e0 - m) : 0.f;
  const float w1 = (lane + 64 < deg) ? expf(e1 - m) : 0.f;
  float s = w0 + w1;
#pragma unroll
  for (int off = 32; off; off >>= 1) s += __shfl_xor(s, off);
  wsh[wv][lane] = w0;
  jsh[wv][lane] = j0;
  wsh[wv][lane + 64] = w1;
  jsh[wv][lane + 64] = j1;
  // ---- gather: 4 neighbors at a time (lane = group*16 + class) ----
  const int c = lane & 15, g = lane >> 4;
  float acc = 0.f;
  int t = g;
  for (; t + 4 < deg; t += 8) {
    const float W0 = wsh[wv][t], W1 = wsh[wv][t + 4];
    const float v0 = h2[(size_t)jsh[wv][t] * 16 + c];
    const float v1 = h2[(size_t)jsh[wv][t + 4] * 16 + c];
    acc = fmaf(W0, v0, fmaf(W1, v1, acc));
  }
  if (t < deg) acc = fmaf(wsh[wv][t], h2[(size_t)jsh[wv][t] * 16 + c], acc);
  acc += __shfl_xor(acc, 16);
  acc += __shfl_xor(acc, 32);
  const float v = acc / s;  // logits
  float mx = v;
#pragma unroll
  for (int off = 8; off; off >>= 1) mx = fmaxf(mx, __shfl_xor(mx, off, 16));
  float se = expf(v - mx);
#pragma unroll
  for (int off = 8; off; off >>= 1) se += __shfl_xor(se, off, 16);
  if (lane < 16) out[(size_t)row * 16 + lane] = v - mx - logf(se);
}

extern "C" void kernel_launch(void* const* d_in, const int* in_sizes, int n_in,
                              void* d_out, int out_size, void* d_ws, size_t ws_size,
                              hipStream_t stream) {
  const float* x = (const float*)d_in[0];
  const int* ei = (const int*)d_in[1];
  const float* W1 = (const float*)d_in[2];
  const float* a1s = (const float*)d_in[3];
  const float* a1d = (const float*)d_in[4];
  const float* W2 = (const float*)d_in[5];
  const float* a2s = (const float*)d_in[6];
  const float* a2d = (const float*)d_in[7];
  float* out = (float*)d_out;
  const int E = in_sizes[1] / 2;

  char* ws = (char*)d_ws;
  unsigned short* h1b = (unsigned short*)ws;           // 4 MB
  float* out1 = (float*)(ws + (8u << 20));             // 8 MB
  unsigned* bitmap = (unsigned*)(ws + (16u << 20));    // 8 MB, reused as CSR
  float* f1s = (float*)(ws + (24u << 20));
  float* f1d = f1s + NN;
  float* h2 = f1d + NN;                                // 512 KB
  float* f2s = h2 + (size_t)NN * 16;
  float* f2d = f2s + NN;
  int* deg = (int*)(f2d + NN);
  unsigned short* w1t = (unsigned short*)(deg + NN);   // 256 KB

  zero_bitmap_kernel<<<2048, 256, 0, stream>>>((uint4*)bitmap);
  scatter_kernel<<<(E + 255) / 256, 256, 0, stream>>>(ei, E, bitmap);
  build_csr_kernel<<<NN / 4, 256, 0, stream>>>(bitmap, deg);
  w1t_kernel<<<512, 256, 0, stream>>>(W1, w1t);
  gemm1_mfma_kernel<<<dim3(NN / 128, 256 / 64), 256, 0, stream>>>(x, w1t, h1b);
  f1_kernel<<<NN / 4, 256, 0, stream>>>(h1b, a1s, a1d, f1s, f1d);
  attn1_kernel<<<NN / 4, 256, 0, stream>>>(bitmap, deg, h1b, f1s, f1d, out1);
  gemm2_kernel<<<NN / 16, 256, 0, stream>>>(out1, W2, h2);
  f2_kernel<<<NN / 256, 256, 0, stream>>>(h2, a2s, a2d, f2s, f2d);
  attn2_kernel<<<NN / 4, 256, 0, stream>>>(bitmap, deg, h2, f2s, f2d, out);
}

// Round 7
// 78.540 us; speedup vs baseline: 1.3201x; 1.1107x over previous
//
#include <hip/hip_runtime.h>
#include <hip/hip_bf16.h>

// GAT, 2 layers, N=8192 nodes, sparse adjacency (~270K edges incl. self-loops).
// Masked softmax with -1e9 fill == sparse neighbor softmax (exp underflows to 0).
// Round 7: out1 stored bf16; gemm2 -> MFMA with fused f2 epilogue (f2 kernel
// gone); zero_bitmap+w1t+w2t merged into one prep kernel. 8 launches total.
// Workspace layout (~26 MB):
//   [0,4MB)    h1b[8192][256] bf16
//   [4,8MB)    out1b[8192][256] bf16 (post-ELU layer-1 output)
//   [16,24MB)  bitmap[8192][256] u32 -> reused as nbr ushort[8192][512]
//   [24MB..)   f1s, f1d, h2[8192][16] f32, f2s, f2d, deg,
//              w1t[256][512] bf16, w2t[16][256] bf16

#define NN 8192
#define MAXD 128  // weight-phase slots; P(in-degree>128) ~ 1e-18 (Poisson 32)

typedef __bf16 bf16x8 __attribute__((ext_vector_type(8)));
typedef float f32x4 __attribute__((ext_vector_type(4)));
typedef unsigned short u16x8 __attribute__((ext_vector_type(8)));

__device__ __forceinline__ unsigned short f2bf(float f) {
  unsigned u = __float_as_uint(f);
  unsigned r = (u + 0x7fffu + ((u >> 16) & 1u)) >> 16;  // round-nearest-even
  return (unsigned short)r;
}
__device__ __forceinline__ float bf2f(unsigned short u) {
  return __uint_as_float(((unsigned)u) << 16);
}
__device__ __forceinline__ float lrelu02(float e) { return e > 0.f ? e : 0.2f * e; }

// ---------- prep: zero bitmap (blocks 0..2047) + W1^T bf16 (2048..2559) + W2^T bf16 (2560) ----------
__global__ __launch_bounds__(256) void prep_kernel(uint4* __restrict__ bitmap,
                                                   const float* __restrict__ W1,
                                                   unsigned short* __restrict__ W1t,
                                                   const float* __restrict__ W2,
                                                   unsigned short* __restrict__ W2t) {
  const int bid = blockIdx.x, tid = threadIdx.x;
  if (bid < 2048) {
    bitmap[bid * 256 + tid] = uint4{0u, 0u, 0u, 0u};
  } else if (bid < 2560) {
    const int gid = (bid - 2048) * 256 + tid;  // 131072 total
    const int n = gid >> 9, k = gid & 511;
    W1t[gid] = f2bf(W1[(size_t)k * 256 + n]);  // W1t[n][k]
  } else {
    for (int i = tid; i < 16 * 256; i += 256) {
      const int n = i >> 8, k = i & 255;
      W2t[i] = f2bf(W2[(size_t)k * 16 + n]);   // W2t[n][k]
    }
  }
}

// ---------- GEMM1 (MFMA): h1b = bf16( x(8192x512) @ W1(512x256) ) ----------
// Block: 256 thr (4 waves), tile BM=128 x BN=64, BK=64, fp32 accum.
// LDS unit map (16B units of 8 bf16): read unit = rb*128 + ks*64 + l
// (lane-sequential -> conflict-free ds_read_b128); staging writes unit
// u(row,c) = (row>>4)*128 + (c>>2)*64 + (c&3)*16 + (row&15), c = 16B k-chunk.
// A and B share the map -> k-permutation cancels in the contraction.
__global__ __launch_bounds__(256) void gemm1_mfma_kernel(
    const float* __restrict__ X, const unsigned short* __restrict__ W1t,
    unsigned short* __restrict__ h1b) {
  constexpr int K = 512;
  __shared__ __align__(16) unsigned short lds[(128 * 64) + (64 * 64)];  // 24 KB
  const int t = threadIdx.x;
  const int w = t >> 6, l = t & 63;
  const int bm = blockIdx.x * 128, bn = blockIdx.y * 64;
  const int r8 = t >> 3, c8 = t & 7;  // staging coords

  f32x4 acc[2][4];
  const f32x4 fz = {0.f, 0.f, 0.f, 0.f};
#pragma unroll
  for (int i = 0; i < 2; ++i)
#pragma unroll
    for (int j = 0; j < 4; ++j) acc[i][j] = fz;

  for (int k0 = 0; k0 < K; k0 += 64) {
    float4 xa[4][2];
#pragma unroll
    for (int p = 0; p < 4; ++p) {
      const float* s = X + (size_t)(bm + r8 + p * 32) * K + k0 + c8 * 8;
      xa[p][0] = *(const float4*)s;
      xa[p][1] = *(const float4*)(s + 4);
    }
    uint4 wb[2];
#pragma unroll
    for (int p = 0; p < 2; ++p)
      wb[p] = *(const uint4*)(W1t + (size_t)(bn + r8 + p * 32) * K + k0 + c8 * 8);
    __syncthreads();  // prev tile's LDS reads done
#pragma unroll
    for (int p = 0; p < 4; ++p) {
      const int row = r8 + p * 32;
      const int u = ((row >> 4) << 7) + ((c8 >> 2) << 6) + ((c8 & 3) << 4) + (row & 15);
      u16x8 v;
      v[0] = f2bf(xa[p][0].x); v[1] = f2bf(xa[p][0].y);
      v[2] = f2bf(xa[p][0].z); v[3] = f2bf(xa[p][0].w);
      v[4] = f2bf(xa[p][1].x); v[5] = f2bf(xa[p][1].y);
      v[6] = f2bf(xa[p][1].z); v[7] = f2bf(xa[p][1].w);
      *(u16x8*)(lds + u * 8) = v;
    }
#pragma unroll
    for (int p = 0; p < 2; ++p) {
      const int col = r8 + p * 32;
      const int u = 1024 + ((col >> 4) << 7) + ((c8 >> 2) << 6) + ((c8 & 3) << 4) + (col & 15);
      *(uint4*)(lds + u * 8) = wb[p];
    }
    __syncthreads();
#pragma unroll
    for (int ks = 0; ks < 2; ++ks) {
      const bf16x8 a0 = *(const bf16x8*)(lds + ((w * 2 + 0) * 128 + ks * 64 + l) * 8);
      const bf16x8 a1 = *(const bf16x8*)(lds + ((w * 2 + 1) * 128 + ks * 64 + l) * 8);
      const bf16x8 b0 = *(const bf16x8*)(lds + (1024 + 0 * 128 + ks * 64 + l) * 8);
      const bf16x8 b1 = *(const bf16x8*)(lds + (1024 + 1 * 128 + ks * 64 + l) * 8);
      const bf16x8 b2 = *(const bf16x8*)(lds + (1024 + 2 * 128 + ks * 64 + l) * 8);
      const bf16x8 b3 = *(const bf16x8*)(lds + (1024 + 3 * 128 + ks * 64 + l) * 8);
      acc[0][0] = __builtin_amdgcn_mfma_f32_16x16x32_bf16(a0, b0, acc[0][0], 0, 0, 0);
      acc[0][1] = __builtin_amdgcn_mfma_f32_16x16x32_bf16(a0, b1, acc[0][1], 0, 0, 0);
      acc[0][2] = __builtin_amdgcn_mfma_f32_16x16x32_bf16(a0, b2, acc[0][2], 0, 0, 0);
      acc[0][3] = __builtin_amdgcn_mfma_f32_16x16x32_bf16(a0, b3, acc[0][3], 0, 0, 0);
      acc[1][0] = __builtin_amdgcn_mfma_f32_16x16x32_bf16(a1, b0, acc[1][0], 0, 0, 0);
      acc[1][1] = __builtin_amdgcn_mfma_f32_16x16x32_bf16(a1, b1, acc[1][1], 0, 0, 0);
      acc[1][2] = __builtin_amdgcn_mfma_f32_16x16x32_bf16(a1, b2, acc[1][2], 0, 0, 0);
      acc[1][3] = __builtin_amdgcn_mfma_f32_16x16x32_bf16(a1, b3, acc[1][3], 0, 0, 0);
    }
  }
  // C/D layout: row=(l>>4)*4+q, col=l&15 (m89-verified)
#pragma unroll
  for (int i = 0; i < 2; ++i)
#pragma unroll
    for (int j = 0; j < 4; ++j)
#pragma unroll
      for (int q = 0; q < 4; ++q) {
        const int row = bm + w * 32 + i * 16 + (l >> 4) * 4 + q;
        const int col = bn + j * 16 + (l & 15);
        h1b[(size_t)row * 256 + col] = f2bf(acc[i][j][q]);
      }
}

// ---------- f1: per-row dots of h1b with a1_src / a1_dst ----------
__global__ __launch_bounds__(256) void f1_kernel(const unsigned short* __restrict__ h1b,
                                                 const float* __restrict__ a_src,
                                                 const float* __restrict__ a_dst,
                                                 float* __restrict__ fs,
                                                 float* __restrict__ fd) {
  const int lane = threadIdx.x & 63;
  const int row = blockIdx.x * 4 + (threadIdx.x >> 6);
  const ushort4 hv = *(const ushort4*)(h1b + (size_t)row * 256 + lane * 4);
  const float h0 = bf2f(hv.x), h1 = bf2f(hv.y), h2 = bf2f(hv.z), h3 = bf2f(hv.w);
  const float4 as = *(const float4*)(a_src + lane * 4);
  const float4 ad = *(const float4*)(a_dst + lane * 4);
  float ss = h0 * as.x + h1 * as.y + h2 * as.z + h3 * as.w;
  float dd = h0 * ad.x + h1 * ad.y + h2 * ad.z + h3 * ad.w;
#pragma unroll
  for (int off = 32; off; off >>= 1) {
    ss += __shfl_xor(ss, off);
    dd += __shfl_xor(dd, off);
  }
  if (lane == 0) {
    fs[row] = ss;
    fd[row] = dd;
  }
}

// ---------- scatter edges into bitmap (dedup via OR) ----------
__global__ void scatter_kernel(const int* __restrict__ ei, int E,
                               unsigned* __restrict__ bitmap) {
  const int t = blockIdx.x * 256 + threadIdx.x;
  if (t >= E) return;
  const int s = ei[t];
  const int d = ei[E + t];
  atomicOr(bitmap + (size_t)s * 256 + (d >> 5), 1u << (d & 31));
}

// ---------- build CSR in place over the bitmap ----------
__global__ __launch_bounds__(256) void build_csr_kernel(unsigned* __restrict__ bitmap,
                                                        int* __restrict__ deg) {
  const int lane = threadIdx.x & 63;
  const int row = blockIdx.x * 4 + (threadIdx.x >> 6);
  unsigned* brow = bitmap + (size_t)row * 256;
  const uint4 wv = *(const uint4*)(brow + lane * 4);
  const int cnt = __popc(wv.x) + __popc(wv.y) + __popc(wv.z) + __popc(wv.w);
  int inc = cnt;
#pragma unroll
  for (int d = 1; d < 64; d <<= 1) {
    const int t = __shfl_up(inc, d);
    if (lane >= d) inc += t;
  }
  int off = inc - cnt;  // exclusive prefix
  const int total = __shfl(inc, 63);
  unsigned short* nb = (unsigned short*)brow;
  const unsigned words[4] = {wv.x, wv.y, wv.z, wv.w};
  const int base_j = lane * 128;
#pragma unroll
  for (int q = 0; q < 4; ++q) {
    unsigned word = words[q];
    while (word) {
      const int b = __ffs(word) - 1;
      word &= word - 1;
      nb[off++] = (unsigned short)(base_j + q * 32 + b);
    }
  }
  if (lane == 0) deg[row] = total;
}

// ---------- layer-1 attention: parallel weights + x4-unrolled bf16 gather ----------
__global__ __launch_bounds__(256) void attn1_kernel(const unsigned* __restrict__ bitmap,
                                                    const int* __restrict__ degarr,
                                                    const unsigned short* __restrict__ h1b,
                                                    const float* __restrict__ fs,
                                                    const float* __restrict__ fd,
                                                    unsigned short* __restrict__ out1b) {
  __shared__ float wsh[4][MAXD];
  __shared__ int jsh[4][MAXD];
  const int lane = threadIdx.x & 63;
  const int wv = threadIdx.x >> 6;
  const int row = blockIdx.x * 4 + wv;
  const unsigned short* nb = (const unsigned short*)(bitmap + (size_t)row * 256);
  const int deg = degarr[row];
  const float fsr = fs[row];
  // ---- weight phase: lane k handles neighbors k and k+64 ----
  const int j0 = (lane < deg) ? (int)nb[lane] : 0;
  const int j1 = (lane + 64 < deg) ? (int)nb[lane + 64] : 0;
  const float e0 = (lane < deg) ? lrelu02(fsr + fd[j0]) : -1e30f;
  const float e1 = (lane + 64 < deg) ? lrelu02(fsr + fd[j1]) : -1e30f;
  float m = fmaxf(e0, e1);
#pragma unroll
  for (int off = 32; off; off >>= 1) m = fmaxf(m, __shfl_xor(m, off));
  const float w0 = (lane < deg) ? expf(e0 - m) : 0.f;
  const float w1 = (lane + 64 < deg) ? expf(e1 - m) : 0.f;
  float s = w0 + w1;
#pragma unroll
  for (int off = 32; off; off >>= 1) s += __shfl_xor(s, off);
  wsh[wv][lane] = w0;
  jsh[wv][lane] = j0;
  wsh[wv][lane + 64] = w1;
  jsh[wv][lane + 64] = j1;
  // same-wave LDS produce->consume; compiler inserts lgkmcnt
  // ---- gather phase: 4 independent 8B loads in flight ----
  float4 acc = {0.f, 0.f, 0.f, 0.f};
  int t = 0;
  for (; t + 4 <= deg; t += 4) {
    const float W0 = wsh[wv][t], W1 = wsh[wv][t + 1], W2 = wsh[wv][t + 2], W3 = wsh[wv][t + 3];
    const int J0 = jsh[wv][t], J1 = jsh[wv][t + 1], J2 = jsh[wv][t + 2], J3 = jsh[wv][t + 3];
    const ushort4 v0 = *(const ushort4*)(h1b + (size_t)J0 * 256 + lane * 4);
    const ushort4 v1 = *(const ushort4*)(h1b + (size_t)J1 * 256 + lane * 4);
    const ushort4 v2 = *(const ushort4*)(h1b + (size_t)J2 * 256 + lane * 4);
    const ushort4 v3 = *(const ushort4*)(h1b + (size_t)J3 * 256 + lane * 4);
    acc.x = fmaf(W0, bf2f(v0.x), fmaf(W1, bf2f(v1.x), fmaf(W2, bf2f(v2.x), fmaf(W3, bf2f(v3.x), acc.x))));
    acc.y = fmaf(W0, bf2f(v0.y), fmaf(W1, bf2f(v1.y), fmaf(W2, bf2f(v2.y), fmaf(W3, bf2f(v3.y), acc.y))));
    acc.z = fmaf(W0, bf2f(v0.z), fmaf(W1, bf2f(v1.z), fmaf(W2, bf2f(v2.z), fmaf(W3, bf2f(v3.z), acc.z))));
    acc.w = fmaf(W0, bf2f(v0.w), fmaf(W1, bf2f(v1.w), fmaf(W2, bf2f(v2.w), fmaf(W3, bf2f(v3.w), acc.w))));
  }
  for (; t < deg; ++t) {
    const float W0 = wsh[wv][t];
    const int J0 = jsh[wv][t];
    const ushort4 v0 = *(const ushort4*)(h1b + (size_t)J0 * 256 + lane * 4);
    acc.x = fmaf(W0, bf2f(v0.x), acc.x);
    acc.y = fmaf(W0, bf2f(v0.y), acc.y);
    acc.z = fmaf(W0, bf2f(v0.z), acc.z);
    acc.w = fmaf(W0, bf2f(v0.w), acc.w);
  }
  const float inv = 1.f / s;
  float4 v = {acc.x * inv, acc.y * inv, acc.z * inv, acc.w * inv};
  v.x = v.x > 0.f ? v.x : expf(v.x) - 1.f;  // elu
  v.y = v.y > 0.f ? v.y : expf(v.y) - 1.f;
  v.z = v.z > 0.f ? v.z : expf(v.z) - 1.f;
  v.w = v.w > 0.f ? v.w : expf(v.w) - 1.f;
  ushort4 o;
  o.x = f2bf(v.x); o.y = f2bf(v.y); o.z = f2bf(v.z); o.w = f2bf(v.w);
  *(ushort4*)(out1b + (size_t)row * 256 + lane * 4) = o;
}

// ---------- GEMM2 (MFMA) + fused f2: h2 = out1b @ W2, fs/fd = h2 . a2 ----------
// 4 waves/block, wave w owns rows [bid*64 + 16w, +16). A from out1b rows,
// B from W2t[16][256]; both use k-map (l>>4)*8+j -> permutation cancels.
__global__ __launch_bounds__(256) void gemm2f2_kernel(
    const unsigned short* __restrict__ out1b, const unsigned short* __restrict__ W2t,
    const float* __restrict__ a2s, const float* __restrict__ a2d,
    float* __restrict__ h2, float* __restrict__ fs, float* __restrict__ fd) {
  const int l = threadIdx.x & 63, w = threadIdx.x >> 6;
  const int row0 = blockIdx.x * 64 + w * 16;
  const int lr = l & 15, lg = l >> 4;
  f32x4 acc = {0.f, 0.f, 0.f, 0.f};
#pragma unroll
  for (int k0 = 0; k0 < 256; k0 += 32) {
    const bf16x8 a = *(const bf16x8*)(out1b + (size_t)(row0 + lr) * 256 + k0 + lg * 8);
    const bf16x8 b = *(const bf16x8*)(W2t + (size_t)lr * 256 + k0 + lg * 8);
    acc = __builtin_amdgcn_mfma_f32_16x16x32_bf16(a, b, acc, 0, 0, 0);
  }
  const float as = a2s[lr], ad = a2d[lr];
#pragma unroll
  for (int q = 0; q < 4; ++q) {
    const int row = row0 + lg * 4 + q;  // C/D: row=(l>>4)*4+q, col=l&15
    const float v = acc[q];
    h2[(size_t)row * 16 + lr] = v;
    float ss = v * as, dd = v * ad;
#pragma unroll
    for (int off = 8; off; off >>= 1) {
      ss += __shfl_xor(ss, off, 16);
      dd += __shfl_xor(dd, off, 16);
    }
    if (lr == 0) {
      fs[row] = ss;
      fd[row] = dd;
    }
  }
}

// ---------- layer-2 attention + final log_softmax over 16 classes ----------
__global__ __launch_bounds__(256) void attn2_kernel(const unsigned* __restrict__ bitmap,
                                                    const int* __restrict__ degarr,
                                                    const float* __restrict__ h2,
                                                    const float* __restrict__ fs,
                                                    const float* __restrict__ fd,
                                                    float* __restrict__ out) {
  __shared__ float wsh[4][MAXD];
  __shared__ int jsh[4][MAXD];
  const int lane = threadIdx.x & 63;
  const int wv = threadIdx.x >> 6;
  const int row = blockIdx.x * 4 + wv;
  const unsigned short* nb = (const unsigned short*)(bitmap + (size_t)row * 256);
  const int deg = degarr[row];
  const float fsr = fs[row];
  const int j0 = (lane < deg) ? (int)nb[lane] : 0;
  const int j1 = (lane + 64 < deg) ? (int)nb[lane + 64] : 0;
  const float e0 = (lane < deg) ? lrelu02(fsr + fd[j0]) : -1e30f;
  const float e1 = (lane + 64 < deg) ? lrelu02(fsr + fd[j1]) : -1e30f;
  float m = fmaxf(e0, e1);
#pragma unroll
  for (int off = 32; off; off >>= 1) m = fmaxf(m, __shfl_xor(m, off));
  const float w0 = (lane < deg) ? expf(e0 - m) : 0.f;
  const float w1 = (lane + 64 < deg) ? expf(e1 - m) : 0.f;
  float s = w0 + w1;
#pragma unroll
  for (int off = 32; off; off >>= 1) s += __shfl_xor(s, off);
  wsh[wv][lane] = w0;
  jsh[wv][lane] = j0;
  wsh[wv][lane + 64] = w1;
  jsh[wv][lane + 64] = j1;
  // ---- gather: 4 neighbors at a time (lane = group*16 + class) ----
  const int c = lane & 15, g = lane >> 4;
  float acc = 0.f;
  int t = g;
  for (; t + 4 < deg; t += 8) {
    const float W0 = wsh[wv][t], W1 = wsh[wv][t + 4];
    const float v0 = h2[(size_t)jsh[wv][t] * 16 + c];
    const float v1 = h2[(size_t)jsh[wv][t + 4] * 16 + c];
    acc = fmaf(W0, v0, fmaf(W1, v1, acc));
  }
  if (t < deg) acc = fmaf(wsh[wv][t], h2[(size_t)jsh[wv][t] * 16 + c], acc);
  acc += __shfl_xor(acc, 16);
  acc += __shfl_xor(acc, 32);
  const float v = acc / s;  // logits
  float mx = v;
#pragma unroll
  for (int off = 8; off; off >>= 1) mx = fmaxf(mx, __shfl_xor(mx, off, 16));
  float se = expf(v - mx);
#pragma unroll
  for (int off = 8; off; off >>= 1) se += __shfl_xor(se, off, 16);
  if (lane < 16) out[(size_t)row * 16 + lane] = v - mx - logf(se);
}

extern "C" void kernel_launch(void* const* d_in, const int* in_sizes, int n_in,
                              void* d_out, int out_size, void* d_ws, size_t ws_size,
                              hipStream_t stream) {
  const float* x = (const float*)d_in[0];
  const int* ei = (const int*)d_in[1];
  const float* W1 = (const float*)d_in[2];
  const float* a1s = (const float*)d_in[3];
  const float* a1d = (const float*)d_in[4];
  const float* W2 = (const float*)d_in[5];
  const float* a2s = (const float*)d_in[6];
  const float* a2d = (const float*)d_in[7];
  float* out = (float*)d_out;
  const int E = in_sizes[1] / 2;

  char* ws = (char*)d_ws;
  unsigned short* h1b = (unsigned short*)ws;           // 4 MB
  unsigned short* out1b = (unsigned short*)(ws + (4u << 20));  // 4 MB
  unsigned* bitmap = (unsigned*)(ws + (16u << 20));    // 8 MB, reused as CSR
  float* f1s = (float*)(ws + (24u << 20));
  float* f1d = f1s + NN;
  float* h2 = f1d + NN;                                // 512 KB
  float* f2s = h2 + (size_t)NN * 16;
  float* f2d = f2s + NN;
  int* deg = (int*)(f2d + NN);
  unsigned short* w1t = (unsigned short*)(deg + NN);   // 256 KB
  unsigned short* w2t = w1t + (size_t)256 * 512;       // 8 KB

  prep_kernel<<<2561, 256, 0, stream>>>((uint4*)bitmap, W1, w1t, W2, w2t);
  scatter_kernel<<<(E + 255) / 256, 256, 0, stream>>>(ei, E, bitmap);
  build_csr_kernel<<<NN / 4, 256, 0, stream>>>(bitmap, deg);
  gemm1_mfma_kernel<<<dim3(NN / 128, 256 / 64), 256, 0, stream>>>(x, w1t, h1b);
  f1_kernel<<<NN / 4, 256, 0, stream>>>(h1b, a1s, a1d, f1s, f1d);
  attn1_kernel<<<NN / 4, 256, 0, stream>>>(bitmap, deg, h1b, f1s, f1d, out1b);
  gemm2f2_kernel<<<NN / 64, 256, 0, stream>>>(out1b, w2t, a2s, a2d, h2, f2s, f2d);
  attn2_kernel<<<NN / 4, 256, 0, stream>>>(bitmap, deg, h2, f2s, f2d, out);
}

// Round 8
// 74.957 us; speedup vs baseline: 1.3832x; 1.0478x over previous
//
#include <hip/hip_runtime.h>
#include <hip/hip_bf16.h>

// GAT, 2 layers, N=8192 nodes, sparse adjacency (~270K edges incl. self-loops).
// Masked softmax with -1e9 fill == sparse neighbor softmax (exp underflows to 0).
// Round 8: attn1 gather = 2 neighbors/wave with 16B/lane loads (half the load
// instrs); f1 fused into gemm1 epilogue (fp32-accurate, -1 kernel); attn2
// gather x4 unrolled. 7 launches.
// Workspace layout (~26 MB):
//   [0,4MB)    h1b[8192][256] bf16
//   [4,8MB)    out1b[8192][256] bf16 (post-ELU layer-1 output)
//   [16,24MB)  bitmap[8192][256] u32 -> reused as nbr ushort[8192][512]
//   [24MB..)   f1s, f1d, h2[8192][16] f32, f2s, f2d, deg,
//              w1t[256][512] bf16, w2t[16][256] bf16

#define NN 8192
#define MAXD 128  // weight-phase slots; P(in-degree>128) ~ 1e-18 (Poisson 32)

typedef __bf16 bf16x8 __attribute__((ext_vector_type(8)));
typedef float f32x4 __attribute__((ext_vector_type(4)));
typedef unsigned short u16x8 __attribute__((ext_vector_type(8)));

__device__ __forceinline__ unsigned short f2bf(float f) {
  unsigned u = __float_as_uint(f);
  unsigned r = (u + 0x7fffu + ((u >> 16) & 1u)) >> 16;  // round-nearest-even
  return (unsigned short)r;
}
__device__ __forceinline__ float bf2f(unsigned short u) {
  return __uint_as_float(((unsigned)u) << 16);
}
__device__ __forceinline__ float lrelu02(float e) { return e > 0.f ? e : 0.2f * e; }

// ---------- prep: zero bitmap + f1s/f1d, W1^T bf16, W2^T bf16 ----------
__global__ __launch_bounds__(256) void prep_kernel(uint4* __restrict__ bitmap,
                                                   const float* __restrict__ W1,
                                                   unsigned short* __restrict__ W1t,
                                                   const float* __restrict__ W2,
                                                   unsigned short* __restrict__ W2t,
                                                   float4* __restrict__ f1sd) {
  const int bid = blockIdx.x, tid = threadIdx.x;
  if (bid < 2048) {
    bitmap[bid * 256 + tid] = uint4{0u, 0u, 0u, 0u};
  } else if (bid < 2560) {
    const int gid = (bid - 2048) * 256 + tid;  // 131072 total
    const int n = gid >> 9, k = gid & 511;
    W1t[gid] = f2bf(W1[(size_t)k * 256 + n]);  // W1t[n][k]
  } else if (bid == 2560) {
    for (int i = tid; i < 16 * 256; i += 256) {
      const int n = i >> 8, k = i & 255;
      W2t[i] = f2bf(W2[(size_t)k * 16 + n]);   // W2t[n][k]
    }
  } else {
    // zero f1s[8192] ++ f1d[8192] (contiguous): 4096 float4
    for (int i = tid; i < 4096; i += 256) f1sd[i] = float4{0.f, 0.f, 0.f, 0.f};
  }
}

// ---------- GEMM1 (MFMA) + fused f1: h1b = bf16(x @ W1); f1s/f1d += partial dots ----------
// Block: 256 thr (4 waves), tile BM=128 x BN=64, BK=64, fp32 accum.
// LDS unit map (16B units of 8 bf16): read unit = rb*128 + ks*64 + l
// (lane-sequential -> conflict-free ds_read_b128); staging writes unit
// u(row,c) = (row>>4)*128 + (c>>2)*64 + (c&3)*16 + (row&15), c = 16B k-chunk.
// A and B share the map -> k-permutation cancels in the contraction.
__global__ __launch_bounds__(256) void gemm1_mfma_kernel(
    const float* __restrict__ X, const unsigned short* __restrict__ W1t,
    unsigned short* __restrict__ h1b, const float* __restrict__ A1S,
    const float* __restrict__ A1D, float* __restrict__ f1s, float* __restrict__ f1d) {
  constexpr int K = 512;
  __shared__ __align__(16) unsigned short lds[(128 * 64) + (64 * 64)];  // 24 KB
  const int t = threadIdx.x;
  const int w = t >> 6, l = t & 63;
  const int bm = blockIdx.x * 128, bn = blockIdx.y * 64;
  const int r8 = t >> 3, c8 = t & 7;  // staging coords

  f32x4 acc[2][4];
  const f32x4 fz = {0.f, 0.f, 0.f, 0.f};
#pragma unroll
  for (int i = 0; i < 2; ++i)
#pragma unroll
    for (int j = 0; j < 4; ++j) acc[i][j] = fz;

  for (int k0 = 0; k0 < K; k0 += 64) {
    float4 xa[4][2];
#pragma unroll
    for (int p = 0; p < 4; ++p) {
      const float* s = X + (size_t)(bm + r8 + p * 32) * K + k0 + c8 * 8;
      xa[p][0] = *(const float4*)s;
      xa[p][1] = *(const float4*)(s + 4);
    }
    uint4 wb[2];
#pragma unroll
    for (int p = 0; p < 2; ++p)
      wb[p] = *(const uint4*)(W1t + (size_t)(bn + r8 + p * 32) * K + k0 + c8 * 8);
    __syncthreads();  // prev tile's LDS reads done
#pragma unroll
    for (int p = 0; p < 4; ++p) {
      const int row = r8 + p * 32;
      const int u = ((row >> 4) << 7) + ((c8 >> 2) << 6) + ((c8 & 3) << 4) + (row & 15);
      u16x8 v;
      v[0] = f2bf(xa[p][0].x); v[1] = f2bf(xa[p][0].y);
      v[2] = f2bf(xa[p][0].z); v[3] = f2bf(xa[p][0].w);
      v[4] = f2bf(xa[p][1].x); v[5] = f2bf(xa[p][1].y);
      v[6] = f2bf(xa[p][1].z); v[7] = f2bf(xa[p][1].w);
      *(u16x8*)(lds + u * 8) = v;
    }
#pragma unroll
    for (int p = 0; p < 2; ++p) {
      const int col = r8 + p * 32;
      const int u = 1024 + ((col >> 4) << 7) + ((c8 >> 2) << 6) + ((c8 & 3) << 4) + (col & 15);
      *(uint4*)(lds + u * 8) = wb[p];
    }
    __syncthreads();
#pragma unroll
    for (int ks = 0; ks < 2; ++ks) {
      const bf16x8 a0 = *(const bf16x8*)(lds + ((w * 2 + 0) * 128 + ks * 64 + l) * 8);
      const bf16x8 a1 = *(const bf16x8*)(lds + ((w * 2 + 1) * 128 + ks * 64 + l) * 8);
      const bf16x8 b0 = *(const bf16x8*)(lds + (1024 + 0 * 128 + ks * 64 + l) * 8);
      const bf16x8 b1 = *(const bf16x8*)(lds + (1024 + 1 * 128 + ks * 64 + l) * 8);
      const bf16x8 b2 = *(const bf16x8*)(lds + (1024 + 2 * 128 + ks * 64 + l) * 8);
      const bf16x8 b3 = *(const bf16x8*)(lds + (1024 + 3 * 128 + ks * 64 + l) * 8);
      acc[0][0] = __builtin_amdgcn_mfma_f32_16x16x32_bf16(a0, b0, acc[0][0], 0, 0, 0);
      acc[0][1] = __builtin_amdgcn_mfma_f32_16x16x32_bf16(a0, b1, acc[0][1], 0, 0, 0);
      acc[0][2] = __builtin_amdgcn_mfma_f32_16x16x32_bf16(a0, b2, acc[0][2], 0, 0, 0);
      acc[0][3] = __builtin_amdgcn_mfma_f32_16x16x32_bf16(a0, b3, acc[0][3], 0, 0, 0);
      acc[1][0] = __builtin_amdgcn_mfma_f32_16x16x32_bf16(a1, b0, acc[1][0], 0, 0, 0);
      acc[1][1] = __builtin_amdgcn_mfma_f32_16x16x32_bf16(a1, b1, acc[1][1], 0, 0, 0);
      acc[1][2] = __builtin_amdgcn_mfma_f32_16x16x32_bf16(a1, b2, acc[1][2], 0, 0, 0);
      acc[1][3] = __builtin_amdgcn_mfma_f32_16x16x32_bf16(a1, b3, acc[1][3], 0, 0, 0);
    }
  }
  // ---- C-write; C/D layout: row=(l>>4)*4+q, col=l&15 (m89-verified) ----
#pragma unroll
  for (int i = 0; i < 2; ++i)
#pragma unroll
    for (int j = 0; j < 4; ++j)
#pragma unroll
      for (int q = 0; q < 4; ++q) {
        const int row = bm + w * 32 + i * 16 + (l >> 4) * 4 + q;
        const int col = bn + j * 16 + (l & 15);
        h1b[(size_t)row * 256 + col] = f2bf(acc[i][j][q]);
      }
  // ---- fused f1: partial dots over this block's 64 cols, atomicAdd per row ----
  const int lc = l & 15;
  float a1sv[4], a1dv[4];
#pragma unroll
  for (int j = 0; j < 4; ++j) {
    a1sv[j] = A1S[bn + j * 16 + lc];
    a1dv[j] = A1D[bn + j * 16 + lc];
  }
#pragma unroll
  for (int i = 0; i < 2; ++i)
#pragma unroll
    for (int q = 0; q < 4; ++q) {
      float ps = 0.f, pd = 0.f;
#pragma unroll
      for (int j = 0; j < 4; ++j) {
        ps = fmaf(acc[i][j][q], a1sv[j], ps);
        pd = fmaf(acc[i][j][q], a1dv[j], pd);
      }
#pragma unroll
      for (int off = 8; off; off >>= 1) {
        ps += __shfl_xor(ps, off, 16);
        pd += __shfl_xor(pd, off, 16);
      }
      if (lc == 0) {
        const int row = bm + w * 32 + i * 16 + (l >> 4) * 4 + q;
        atomicAdd(f1s + row, ps);
        atomicAdd(f1d + row, pd);
      }
    }
}

// ---------- scatter edges into bitmap (dedup via OR) ----------
__global__ void scatter_kernel(const int* __restrict__ ei, int E,
                               unsigned* __restrict__ bitmap) {
  const int t = blockIdx.x * 256 + threadIdx.x;
  if (t >= E) return;
  const int s = ei[t];
  const int d = ei[E + t];
  atomicOr(bitmap + (size_t)s * 256 + (d >> 5), 1u << (d & 31));
}

// ---------- build CSR in place over the bitmap ----------
__global__ __launch_bounds__(256) void build_csr_kernel(unsigned* __restrict__ bitmap,
                                                        int* __restrict__ deg) {
  const int lane = threadIdx.x & 63;
  const int row = blockIdx.x * 4 + (threadIdx.x >> 6);
  unsigned* brow = bitmap + (size_t)row * 256;
  const uint4 wv = *(const uint4*)(brow + lane * 4);
  const int cnt = __popc(wv.x) + __popc(wv.y) + __popc(wv.z) + __popc(wv.w);
  int inc = cnt;
#pragma unroll
  for (int d = 1; d < 64; d <<= 1) {
    const int t = __shfl_up(inc, d);
    if (lane >= d) inc += t;
  }
  int off = inc - cnt;  // exclusive prefix
  const int total = __shfl(inc, 63);
  unsigned short* nb = (unsigned short*)brow;
  const unsigned words[4] = {wv.x, wv.y, wv.z, wv.w};
  const int base_j = lane * 128;
#pragma unroll
  for (int q = 0; q < 4; ++q) {
    unsigned word = words[q];
    while (word) {
      const int b = __ffs(word) - 1;
      word &= word - 1;
      nb[off++] = (unsigned short)(base_j + q * 32 + b);
    }
  }
  if (lane == 0) deg[row] = total;
}

// ---------- layer-1 attention: parallel weights; gather = 2 nbrs/wave, 16B/lane ----------
__global__ __launch_bounds__(256) void attn1_kernel(const unsigned* __restrict__ bitmap,
                                                    const int* __restrict__ degarr,
                                                    const unsigned short* __restrict__ h1b,
                                                    const float* __restrict__ fs,
                                                    const float* __restrict__ fd,
                                                    unsigned short* __restrict__ out1b) {
  __shared__ float wsh[4][MAXD];
  __shared__ int jsh[4][MAXD];
  const int lane = threadIdx.x & 63;
  const int wv = threadIdx.x >> 6;
  const int row = blockIdx.x * 4 + wv;
  const unsigned short* nb = (const unsigned short*)(bitmap + (size_t)row * 256);
  const int deg = degarr[row];
  const float fsr = fs[row];
  // ---- weight phase: lane k handles neighbors k and k+64 ----
  const int j0 = (lane < deg) ? (int)nb[lane] : 0;
  const int j1 = (lane + 64 < deg) ? (int)nb[lane + 64] : 0;
  const float e0 = (lane < deg) ? lrelu02(fsr + fd[j0]) : -1e30f;
  const float e1 = (lane + 64 < deg) ? lrelu02(fsr + fd[j1]) : -1e30f;
  float m = fmaxf(e0, e1);
#pragma unroll
  for (int off = 32; off; off >>= 1) m = fmaxf(m, __shfl_xor(m, off));
  const float w0 = (lane < deg) ? expf(e0 - m) : 0.f;
  const float w1 = (lane + 64 < deg) ? expf(e1 - m) : 0.f;
  float s = w0 + w1;
#pragma unroll
  for (int off = 32; off; off >>= 1) s += __shfl_xor(s, off);
  wsh[wv][lane] = w0;
  jsh[wv][lane] = j0;
  wsh[wv][lane + 64] = w1;
  jsh[wv][lane + 64] = j1;
  // same-wave LDS produce->consume; compiler inserts lgkmcnt
  // ---- gather: halves of the wave take alternating neighbors; 16B per lane ----
  const int half = lane >> 5, lh = lane & 31;
  float acc[8] = {0.f, 0.f, 0.f, 0.f, 0.f, 0.f, 0.f, 0.f};
  int t = 0;
  for (; t + 8 <= deg; t += 8) {  // 4 pairs -> 4 independent 16B loads in flight
    const int ja = jsh[wv][t + half], jb = jsh[wv][t + 2 + half];
    const int jc = jsh[wv][t + 4 + half], jd = jsh[wv][t + 6 + half];
    const float Wa = wsh[wv][t + half], Wb = wsh[wv][t + 2 + half];
    const float Wc = wsh[wv][t + 4 + half], Wd = wsh[wv][t + 6 + half];
    const u16x8 va = *(const u16x8*)(h1b + (size_t)ja * 256 + lh * 8);
    const u16x8 vb = *(const u16x8*)(h1b + (size_t)jb * 256 + lh * 8);
    const u16x8 vc = *(const u16x8*)(h1b + (size_t)jc * 256 + lh * 8);
    const u16x8 vd = *(const u16x8*)(h1b + (size_t)jd * 256 + lh * 8);
#pragma unroll
    for (int e = 0; e < 8; ++e)
      acc[e] = fmaf(Wa, bf2f(va[e]),
               fmaf(Wb, bf2f(vb[e]), fmaf(Wc, bf2f(vc[e]), fmaf(Wd, bf2f(vd[e]), acc[e]))));
  }
  for (; t < deg; t += 2) {  // tail pairs (odd tail: half 1 gets weight 0)
    const int idx = t + half;
    const int jt = (idx < deg) ? jsh[wv][idx] : 0;
    const float Wt = (idx < deg) ? wsh[wv][idx] : 0.f;
    const u16x8 v = *(const u16x8*)(h1b + (size_t)jt * 256 + lh * 8);
#pragma unroll
    for (int e = 0; e < 8; ++e) acc[e] = fmaf(Wt, bf2f(v[e]), acc[e]);
  }
  // combine the two halves
#pragma unroll
  for (int e = 0; e < 8; ++e) acc[e] += __shfl_xor(acc[e], 32);
  const float inv = 1.f / s;
  u16x8 o;
#pragma unroll
  for (int e = 0; e < 8; ++e) {
    float v = acc[e] * inv;
    v = v > 0.f ? v : expf(v) - 1.f;  // elu
    o[e] = f2bf(v);
  }
  if (lane < 32) *(u16x8*)(out1b + (size_t)row * 256 + lh * 8) = o;
}

// ---------- GEMM2 (MFMA) + fused f2: h2 = out1b @ W2, fs/fd = h2 . a2 ----------
// 4 waves/block, wave w owns rows [bid*64 + 16w, +16). A from out1b rows,
// B from W2t[16][256]; both use k-map (l>>4)*8+j -> permutation cancels.
__global__ __launch_bounds__(256) void gemm2f2_kernel(
    const unsigned short* __restrict__ out1b, const unsigned short* __restrict__ W2t,
    const float* __restrict__ a2s, const float* __restrict__ a2d,
    float* __restrict__ h2, float* __restrict__ fs, float* __restrict__ fd) {
  const int l = threadIdx.x & 63, w = threadIdx.x >> 6;
  const int row0 = blockIdx.x * 64 + w * 16;
  const int lr = l & 15, lg = l >> 4;
  f32x4 acc = {0.f, 0.f, 0.f, 0.f};
#pragma unroll
  for (int k0 = 0; k0 < 256; k0 += 32) {
    const bf16x8 a = *(const bf16x8*)(out1b + (size_t)(row0 + lr) * 256 + k0 + lg * 8);
    const bf16x8 b = *(const bf16x8*)(W2t + (size_t)lr * 256 + k0 + lg * 8);
    acc = __builtin_amdgcn_mfma_f32_16x16x32_bf16(a, b, acc, 0, 0, 0);
  }
  const float as = a2s[lr], ad = a2d[lr];
#pragma unroll
  for (int q = 0; q < 4; ++q) {
    const int row = row0 + lg * 4 + q;  // C/D: row=(l>>4)*4+q, col=l&15
    const float v = acc[q];
    h2[(size_t)row * 16 + lr] = v;
    float ss = v * as, dd = v * ad;
#pragma unroll
    for (int off = 8; off; off >>= 1) {
      ss += __shfl_xor(ss, off, 16);
      dd += __shfl_xor(dd, off, 16);
    }
    if (lr == 0) {
      fs[row] = ss;
      fd[row] = dd;
    }
  }
}

// ---------- layer-2 attention + final log_softmax over 16 classes ----------
__global__ __launch_bounds__(256) void attn2_kernel(const unsigned* __restrict__ bitmap,
                                                    const int* __restrict__ degarr,
                                                    const float* __restrict__ h2,
                                                    const float* __restrict__ fs,
                                                    const float* __restrict__ fd,
                                                    float* __restrict__ out) {
  __shared__ float wsh[4][MAXD];
  __shared__ int jsh[4][MAXD];
  const int lane = threadIdx.x & 63;
  const int wv = threadIdx.x >> 6;
  const int row = blockIdx.x * 4 + wv;
  const unsigned short* nb = (const unsigned short*)(bitmap + (size_t)row * 256);
  const int deg = degarr[row];
  const float fsr = fs[row];
  const int j0 = (lane < deg) ? (int)nb[lane] : 0;
  const int j1 = (lane + 64 < deg) ? (int)nb[lane + 64] : 0;
  const float e0 = (lane < deg) ? lrelu02(fsr + fd[j0]) : -1e30f;
  const float e1 = (lane + 64 < deg) ? lrelu02(fsr + fd[j1]) : -1e30f;
  float m = fmaxf(e0, e1);
#pragma unroll
  for (int off = 32; off; off >>= 1) m = fmaxf(m, __shfl_xor(m, off));
  const float w0 = (lane < deg) ? expf(e0 - m) : 0.f;
  const float w1 = (lane + 64 < deg) ? expf(e1 - m) : 0.f;
  float s = w0 + w1;
#pragma unroll
  for (int off = 32; off; off >>= 1) s += __shfl_xor(s, off);
  wsh[wv][lane] = w0;
  jsh[wv][lane] = j0;
  wsh[wv][lane + 64] = w1;
  jsh[wv][lane + 64] = j1;
  // ---- gather: 4 neighbors at a time (lane = group*16 + class), x4 in flight ----
  const int c = lane & 15, g = lane >> 4;
  float acc = 0.f;
  int t = g;
  for (; t + 12 < deg; t += 16) {
    const float W0 = wsh[wv][t], W1 = wsh[wv][t + 4];
    const float W2 = wsh[wv][t + 8], W3 = wsh[wv][t + 12];
    const float v0 = h2[(size_t)jsh[wv][t] * 16 + c];
    const float v1 = h2[(size_t)jsh[wv][t + 4] * 16 + c];
    const float v2 = h2[(size_t)jsh[wv][t + 8] * 16 + c];
    const float v3 = h2[(size_t)jsh[wv][t + 12] * 16 + c];
    acc = fmaf(W0, v0, fmaf(W1, v1, fmaf(W2, v2, fmaf(W3, v3, acc))));
  }
  for (; t < deg; t += 4) acc = fmaf(wsh[wv][t], h2[(size_t)jsh[wv][t] * 16 + c], acc);
  acc += __shfl_xor(acc, 16);
  acc += __shfl_xor(acc, 32);
  const float v = acc / s;  // logits
  float mx = v;
#pragma unroll
  for (int off = 8; off; off >>= 1) mx = fmaxf(mx, __shfl_xor(mx, off, 16));
  float se = expf(v - mx);
#pragma unroll
  for (int off = 8; off; off >>= 1) se += __shfl_xor(se, off, 16);
  if (lane < 16) out[(size_t)row * 16 + lane] = v - mx - logf(se);
}

extern "C" void kernel_launch(void* const* d_in, const int* in_sizes, int n_in,
                              void* d_out, int out_size, void* d_ws, size_t ws_size,
                              hipStream_t stream) {
  const float* x = (const float*)d_in[0];
  const int* ei = (const int*)d_in[1];
  const float* W1 = (const float*)d_in[2];
  const float* a1s = (const float*)d_in[3];
  const float* a1d = (const float*)d_in[4];
  const float* W2 = (const float*)d_in[5];
  const float* a2s = (const float*)d_in[6];
  const float* a2d = (const float*)d_in[7];
  float* out = (float*)d_out;
  const int E = in_sizes[1] / 2;

  char* ws = (char*)d_ws;
  unsigned short* h1b = (unsigned short*)ws;           // 4 MB
  unsigned short* out1b = (unsigned short*)(ws + (4u << 20));  // 4 MB
  unsigned* bitmap = (unsigned*)(ws + (16u << 20));    // 8 MB, reused as CSR
  float* f1s = (float*)(ws + (24u << 20));
  float* f1d = f1s + NN;
  float* h2 = f1d + NN;                                // 512 KB
  float* f2s = h2 + (size_t)NN * 16;
  float* f2d = f2s + NN;
  int* deg = (int*)(f2d + NN);
  unsigned short* w1t = (unsigned short*)(deg + NN);   // 256 KB
  unsigned short* w2t = w1t + (size_t)256 * 512;       // 8 KB

  prep_kernel<<<2562, 256, 0, stream>>>((uint4*)bitmap, W1, w1t, W2, w2t, (float4*)f1s);
  scatter_kernel<<<(E + 255) / 256, 256, 0, stream>>>(ei, E, bitmap);
  build_csr_kernel<<<NN / 4, 256, 0, stream>>>(bitmap, deg);
  gemm1_mfma_kernel<<<dim3(NN / 128, 256 / 64), 256, 0, stream>>>(x, w1t, h1b, a1s, a1d,
                                                                  f1s, f1d);
  attn1_kernel<<<NN / 4, 256, 0, stream>>>(bitmap, deg, h1b, f1s, f1d, out1b);
  gemm2f2_kernel<<<NN / 64, 256, 0, stream>>>(out1b, w2t, a2s, a2d, h2, f2s, f2d);
  attn2_kernel<<<NN / 4, 256, 0, stream>>>(bitmap, deg, h2, f2s, f2d, out);
}